// Round 1
// 224.660 us; speedup vs baseline: 1.0246x; 1.0246x over previous
//
#include <hip/hip_runtime.h>
#include <math.h>

#define NN 20000
#define NE 640000
#define D  128
#define NSLICE 2500        // NN / 8 XCDs
#define NTILES 625         // NN / 32 rows per GEMM tile (exact)
#define SEG 128            // per-node bump-allocated segment (max degree; mean 32)

typedef __attribute__((ext_vector_type(8))) short short8;
typedef __attribute__((ext_vector_type(4))) float floatx4;

static __device__ __forceinline__ unsigned short f2bf(float f) {
    union { float f; unsigned int u; } v; v.f = f;
    unsigned int u = v.u;
    u += 0x7fff + ((u >> 16) & 1);   // round-to-nearest-even
    return (unsigned short)(u >> 16);
}
static __device__ __forceinline__ unsigned int pack2bf(float a, float b) {
    return (unsigned int)f2bf(a) | ((unsigned int)f2bf(b) << 16);
}
static __device__ __forceinline__ float bf_lo(unsigned int u) {
    union { unsigned int i; float f; } v; v.i = u << 16; return v.f;
}
static __device__ __forceinline__ float bf_hi(unsigned int u) {
    union { unsigned int i; float f; } v; v.i = u & 0xffff0000u; return v.f;
}
static __device__ __forceinline__ float sigm(float x) { return 1.f / (1.f + __expf(-x)); }
static __device__ __forceinline__ float tanhx(float x) { return 1.f - 2.f / (__expf(2.f * x) + 1.f); }

static __device__ __forceinline__ void load_lds16(const void* g, void* l) {
    __builtin_amdgcn_global_load_lds(
        (const __attribute__((address_space(1))) unsigned int*)g,
        (__attribute__((address_space(3))) unsigned int*)l, 16, 0, 0);
}

// Fused prep + CSR fill (bump allocation -> no scan pass):
//  (a) grid-stride: X/H -> bf16 pack into XH; weight transpose into the
//      LDS-image swizzled Wsz layout; bias fuse.
//  (b) XCD-sliced fill: block b handles dst-slice s=b&7 over an 8000-edge
//      chunk; entry s_p[d*SEG + p], p = atomicAdd(&cnt[d],1). A node's 512 B
//      segment is written only from its slice's blocks -> single-XCD line
//      dirtying (no cross-XCD write-back amplification).
// Wsz layout (shorts): idx = ci*16384 + jg*4096 + col*8 + off, k = ci*32+jg*8+off.
__global__ void __launch_bounds__(256)
prep_fill_kernel(const int* __restrict__ src, const int* __restrict__ dst,
                 const float* __restrict__ ew, int* __restrict__ cnt,
                 unsigned int* __restrict__ s_p,
                 const float4* __restrict__ X4, const float4* __restrict__ H4,
                 unsigned int* __restrict__ XH32,
                 const float* __restrict__ Wx_l, const float* __restrict__ Wx_r,
                 const float* __restrict__ Wh_l, const float* __restrict__ Wh_r,
                 const float* __restrict__ bx, const float* __restrict__ bh,
                 const float* __restrict__ bg,
                 unsigned short* __restrict__ Wsz, float* __restrict__ bias) {
    int tid = threadIdx.x, b = blockIdx.x;       // 640 blocks x 256 threads
    // (a) packing, grid-stride (4 iters)
    for (int t = b * 256 + tid; t < NE; t += 640 * 256) {
        float4 x = X4[t];
        float4 h = H4[t];
        int n = t >> 5, q = t & 31;
        unsigned int* row = XH32 + n * 128;
        row[2 * q]          = pack2bf(x.x, x.y);
        row[2 * q + 1]      = pack2bf(x.z, x.w);
        row[64 + 2 * q]     = pack2bf(h.x, h.y);
        row[64 + 2 * q + 1] = pack2bf(h.z, h.w);
        if (t < 512 * 512) {
            int j = t >> 9, k = t & 511, g = j >> 7, o = j & 127;
            float w;
            if (k < 128)      w = Wx_l[g * 16384 + k * 128 + o];
            else if (k < 256) w = Wx_r[g * 16384 + (k - 128) * 128 + o];
            else if (k < 384) w = Wh_l[g * 16384 + (k - 256) * 128 + o];
            else              w = Wh_r[g * 16384 + (k - 384) * 128 + o];
            int ci = k >> 5, jg = (k >> 3) & 3, off = k & 7;
            Wsz[ci * 16384 + jg * 4096 + j * 8 + off] = f2bf(w);
            if (k == 0) bias[j] = bx[g * 128 + o] + bh[g * 128 + o] + bg[g * 128 + o];
        }
    }
    // (b) slice-filtered bump fill
    int s = b & 7, chunk = b >> 3;               // 80 chunks x 8000 edges
    int lo = s * NSLICE, hi = lo + NSLICE;
    int e0 = chunk * 8000;
    for (int e = e0 + tid; e < e0 + 8000; e += 256) {
        int d = dst[e];
        if (d >= lo && d < hi) {
            int p = atomicAdd(&cnt[d], 1);
            if (p < SEG) s_p[d * SEG + p] = (unsigned int)src[e] | ((unsigned int)f2bf(ew[e]) << 16);
        }
    }
}

// One wave per node (lane owns 8 B of the 512 B row). 16-edge manual unroll:
// 16 independent row gathers in flight per lane. Block->node mapping matches
// fill's XCD slicing so segment reads hit the local L2.
__global__ void __launch_bounds__(256)
aggregate_kernel(const uint2* __restrict__ XH64,
                 const int* __restrict__ cnt,
                 const unsigned int* __restrict__ s_p,
                 uint2* __restrict__ AGG64) {
    int wv = threadIdx.x >> 6, lane = threadIdx.x & 63;
    int b = blockIdx.x;                 // 0..4999
    int s = b & 7, j = b >> 3;          // j: 0..624
    int n = s * NSLICE + j * 4 + wv;
    int deg = cnt[n];
    int m = (deg < SEG) ? deg : SEG;
    const unsigned int* seg = s_p + (size_t)n * SEG;
    float a0 = 0.f, a1 = 0.f, a2 = 0.f, a3 = 0.f;
    int i = 0;
    for (; i + 16 <= m; i += 16) {
        unsigned int e[16];
        uint2 u[16];
#pragma unroll
        for (int k = 0; k < 16; ++k) e[k] = seg[i + k];
#pragma unroll
        for (int k = 0; k < 16; ++k) u[k] = XH64[(size_t)(e[k] & 0xffff) * 64 + lane];
#pragma unroll
        for (int k = 0; k < 16; ++k) {
            float w = __int_as_float(e[k] & 0xffff0000u);
            a0 += bf_lo(u[k].x) * w;
            a1 += bf_hi(u[k].x) * w;
            a2 += bf_lo(u[k].y) * w;
            a3 += bf_hi(u[k].y) * w;
        }
    }
    for (; i + 4 <= m; i += 4) {
        unsigned int e[4];
        uint2 u[4];
#pragma unroll
        for (int k = 0; k < 4; ++k) e[k] = seg[i + k];
#pragma unroll
        for (int k = 0; k < 4; ++k) u[k] = XH64[(size_t)(e[k] & 0xffff) * 64 + lane];
#pragma unroll
        for (int k = 0; k < 4; ++k) {
            float w = __int_as_float(e[k] & 0xffff0000u);
            a0 += bf_lo(u[k].x) * w;
            a1 += bf_hi(u[k].x) * w;
            a2 += bf_lo(u[k].y) * w;
            a3 += bf_hi(u[k].y) * w;
        }
    }
    for (; i < m; ++i) {
        unsigned int e = seg[i];
        float w = __int_as_float(e & 0xffff0000u);
        uint2 u = XH64[(size_t)(e & 0xffff) * 64 + lane];
        a0 += bf_lo(u.x) * w;
        a1 += bf_hi(u.x) * w;
        a2 += bf_lo(u.y) * w;
        a3 += bf_hi(u.y) * w;
    }
    float inv = (deg > 0) ? 1.0f / (float)deg : 1.0f;
    uint2 r;
    r.x = pack2bf(a0 * inv, a1 * inv);
    r.y = pack2bf(a2 * inv, a3 * inv);
    AGG64[(size_t)n * 64 + lane] = r;
}

// Fused GEMM + peephole-LSTM, N-split for occupancy.
// 1250 blocks = 625 M-tiles x 2 column-halves. Block (t,h) computes rows
// [t*32, t*32+32) x output cols cg0 in [h*64, h*64+64) for ALL 4 gates
// (256 of the 512 GEMM cols) -> the in-register LSTM epilogue still holds.
// LDS: double-buffered 2 x 16 KB (was 2 x 32 KB) -> 32 KB/block, so
// occupancy is VGPR-step bound at 4 blocks/CU (16 waves/CU) instead of
// LDS-bound at 2 blocks/CU. 1250 blocks over 256 CUs also kills the
// 113-block tail round the old 625-block grid had.
// Per iter, wave wv stages pieces (jg=wv, g=0..3): 4 x global_load_lds
// dwordx4 of the contiguous 1 KB column-half slices of Wsz.
__global__ void __launch_bounds__(256)
gemm_lstm_kernel(const unsigned short* __restrict__ XH,
                 const unsigned short* __restrict__ AGG,
                 const unsigned short* __restrict__ Wsz,
                 const float* __restrict__ bias,
                 const float* __restrict__ wc,
                 const float* __restrict__ C,
                 float* __restrict__ out) {
    __shared__ __align__(16) short Bs[2][8192];  // [buf][jg*2048 + g*512 + c64*8 + off]

    int tid = threadIdx.x;
    int wv = tid >> 6, lane = tid & 63;
    int lm = lane & 15, lq = lane >> 4;
    int bid = blockIdx.x;
    int m0 = (bid >> 1) * 32;
    int hb = (bid & 1) * 512;           // half-offset in shorts: h*64 cols * 8

    floatx4 acc[2][4];
#pragma unroll
    for (int mt = 0; mt < 2; ++mt)
#pragma unroll
        for (int g = 0; g < 4; ++g) acc[mt][g] = (floatx4)(0.f);

    // stage chunk 0 into buf 0: wave wv stages (jg=wv, g=0..3), 1 KB each
#pragma unroll
    for (int g = 0; g < 4; ++g)
        load_lds16(Wsz + wv * 4096 + g * 1024 + hb + lane * 8,
                   &Bs[0][wv * 2048 + g * 512]);

    // A prefetch for kb=0 (segment aggX, offset 0 in AGG)
    short8 ca0, ca1;
    {
        const unsigned short* ar = AGG + (size_t)(m0 + lm) * 256 + lq * 8;
        ca0 = *(const short8*)ar;
        ca1 = *(const short8*)(ar + 16 * 256);
    }

    for (int it = 0; it < 16; ++it) {
        __syncthreads();   // drains staging (vmcnt0) + guards buffer reuse
        if (it < 15) {
            const unsigned short* wb = Wsz + (it + 1) * 16384 + wv * 4096 + hb;
            short* lb = &Bs[(it + 1) & 1][wv * 2048];
#pragma unroll
            for (int g = 0; g < 4; ++g)
                load_lds16(wb + g * 1024 + lane * 8, &lb[g * 512]);
        }
        // A prefetch for next iter
        short8 na0, na1;
        if (it < 15) {
            int kn = (it + 1) * 32;
            const unsigned short* ab = (kn & 128) ? XH : AGG;
            int aoff = (kn & 127) | ((kn & 256) >> 1);
            const unsigned short* arn = ab + (size_t)(m0 + lm) * 256 + aoff + lq * 8;
            na0 = *(const short8*)arn;
            na1 = *(const short8*)(arn + 16 * 256);
        }
        // B frags from LDS (conflict-free) + MFMA
        const short* bsc = Bs[it & 1];
#pragma unroll
        for (int g = 0; g < 4; ++g) {
            short8 bfr = *(const short8*)&bsc[(lq << 11) + (g << 9) + ((wv << 4) + lm) * 8];
            acc[0][g] = __builtin_amdgcn_mfma_f32_16x16x32_bf16(ca0, bfr, acc[0][g], 0, 0, 0);
            acc[1][g] = __builtin_amdgcn_mfma_f32_16x16x32_bf16(ca1, bfr, acc[1][g], 0, 0, 0);
        }
        ca0 = na0; ca1 = na1;
    }

    // epilogue: bias/peephole loads here (keeps K-loop register pressure low)
    int cg0 = (hb >> 3) + (wv << 4) + lm;   // hb/8 = h*64
    float bG[4], wP[3];
#pragma unroll
    for (int g = 0; g < 4; ++g) bG[g] = bias[(g << 7) + cg0];
#pragma unroll
    for (int j = 0; j < 3; ++j) wP[j] = wc[j * 128 + cg0];

#pragma unroll
    for (int mt = 0; mt < 2; ++mt)
#pragma unroll
        for (int r = 0; r < 4; ++r) {
            int row = m0 + mt * 16 + lq * 4 + r;   // 625*32 == NN exact, no guard
            float c = C[(size_t)row * D + cg0];
            float pi = acc[mt][0][r] + bG[0] + wP[0] * c;
            float pf = acc[mt][1][r] + bG[1] + wP[1] * c;
            float pt = acc[mt][2][r] + bG[2];
            float po = acc[mt][3][r] + bG[3];
            float I = sigm(pi);
            float F = sigm(pf);
            float T = tanhx(pt);
            float cn = F * c + I * T;
            float O = sigm(po + wP[2] * cn);
            out[(size_t)row * D + cg0] = O * tanhx(cn);
            out[(size_t)NN * D + (size_t)row * D + cg0] = cn;
        }
}

extern "C" void kernel_launch(void* const* d_in, const int* in_sizes, int n_in,
                              void* d_out, int out_size, void* d_ws, size_t ws_size,
                              hipStream_t stream) {
    const float* X  = (const float*)d_in[0];
    const int* ei   = (const int*)d_in[1];
    const float* ew = (const float*)d_in[2];
    const float* H  = (const float*)d_in[3];
    const float* C  = (const float*)d_in[4];
    const float* Wx_l = (const float*)d_in[5];
    const float* Wx_r = (const float*)d_in[6];
    const float* bx   = (const float*)d_in[7];
    const float* Wh_l = (const float*)d_in[8];
    const float* Wh_r = (const float*)d_in[9];
    const float* bh   = (const float*)d_in[10];
    const float* wc   = (const float*)d_in[11];
    const float* bg   = (const float*)d_in[12];
    float* out = (float*)d_out;

    const int* src = ei;
    const int* dst = ei + NE;

    // workspace layout (16B aligned), ~31.3 MB
    char* ws = (char*)d_ws;
    int* cnt = (int*)(ws + 0);                                //     80,000 B
    unsigned int* s_p = (unsigned int*)(ws + 80128);          // 10,240,000 B (20000*128*4)
    unsigned short* XH  = (unsigned short*)(ws + 10320128);   // 10,240,000 B
    unsigned short* AGG = (unsigned short*)(ws + 20560128);   // 10,240,000 B
    unsigned short* Wsz = (unsigned short*)(ws + 30800128);   //    524,288 B
    float* bias = (float*)(ws + 31324416);                    //      2,048 B

    hipMemsetAsync(cnt, 0, NN * sizeof(int), stream);
    prep_fill_kernel<<<640, 256, 0, stream>>>(src, dst, ew, cnt, s_p,
                                              (const float4*)X, (const float4*)H,
                                              (unsigned int*)XH,
                                              Wx_l, Wx_r, Wh_l, Wh_r,
                                              bx, bh, bg, Wsz, bias);
    aggregate_kernel<<<NN / 4, 256, 0, stream>>>((const uint2*)XH, cnt, s_p,
                                                 (uint2*)AGG);
    gemm_lstm_kernel<<<NTILES * 2, 256, 0, stream>>>(XH, AGG, Wsz, bias, wc, C, out);
}

// Round 2
// 207.338 us; speedup vs baseline: 1.1101x; 1.0835x over previous
//
#include <hip/hip_runtime.h>
#include <math.h>

#define NN 20000
#define NE 640000
#define D  128
#define NSLICE 2500        // NN / 8 XCDs
#define NTILES 625         // NN / 32 rows per GEMM tile (exact)
#define SEG 128            // per-node bump-allocated segment (max degree; mean 32)
#define NCHUNK 640         // fill chunks
#define CHUNK 1000         // edges per chunk (640*1000 = NE)

typedef __attribute__((ext_vector_type(8))) short short8;
typedef __attribute__((ext_vector_type(4))) float floatx4;

static __device__ __forceinline__ unsigned short f2bf(float f) {
    union { float f; unsigned int u; } v; v.f = f;
    unsigned int u = v.u;
    u += 0x7fff + ((u >> 16) & 1);   // round-to-nearest-even
    return (unsigned short)(u >> 16);
}
static __device__ __forceinline__ unsigned int pack2bf(float a, float b) {
    return (unsigned int)f2bf(a) | ((unsigned int)f2bf(b) << 16);
}
static __device__ __forceinline__ float bf_lo(unsigned int u) {
    union { unsigned int i; float f; } v; v.i = u << 16; return v.f;
}
static __device__ __forceinline__ float bf_hi(unsigned int u) {
    union { unsigned int i; float f; } v; v.i = u & 0xffff0000u; return v.f;
}
static __device__ __forceinline__ float sigm(float x) { return 1.f / (1.f + __expf(-x)); }
static __device__ __forceinline__ float tanhx(float x) { return 1.f - 2.f / (__expf(2.f * x) + 1.f); }

static __device__ __forceinline__ void load_lds16(const void* g, void* l) {
    __builtin_amdgcn_global_load_lds(
        (const __attribute__((address_space(1))) unsigned int*)g,
        (__attribute__((address_space(3))) unsigned int*)l, 16, 0, 0);
}

// Fused prep + CSR fill, rebuilt for TLP (R2):
//  5120 blocks (was 640): VGPR=16, LDS=0 -> 8 blocks/CU resident = 32 waves/CU.
//  (a) blocks 0..2559: X/H bf16 pack, one element per thread.
//  (a') blocks 2560..2815: weight transpose via COALESCED float4 reads along
//       the output dim (was a 64-line/wave stride-512B gather), 4 short
//       stores each; bias fuse on k==0 rows.
//  (b) all blocks: slice-filtered bump fill, 640 chunks x 1000 edges x
//      8 slices. Per thread: one int4 dst + int4 src + float4 ew coalesced
//      load (unconditional: line-occupancy of the old conditional scalar
//      gathers was ~88% anyway), then 4 independent filter->atomic->store
//      chains. Slice s = b&7 matches XCD id -> single-XCD segment dirtying.
// Wsz layout (shorts): idx = ci*16384 + jg*4096 + col*8 + off, k = ci*32+jg*8+off.
__global__ void __launch_bounds__(256)
prep_fill_kernel(const int* __restrict__ src, const int* __restrict__ dst,
                 const float* __restrict__ ew, int* __restrict__ cnt,
                 unsigned int* __restrict__ s_p,
                 const float4* __restrict__ X4, const float4* __restrict__ H4,
                 unsigned int* __restrict__ XH32,
                 const float* __restrict__ Wx_l, const float* __restrict__ Wx_r,
                 const float* __restrict__ Wh_l, const float* __restrict__ Wh_r,
                 const float* __restrict__ bx, const float* __restrict__ bh,
                 const float* __restrict__ bg,
                 unsigned short* __restrict__ Wsz, float* __restrict__ bias) {
    int tid = threadIdx.x, b = blockIdx.x;       // 5120 blocks x 256 threads

    // (b) edge loads first so they are in flight under the (a) work
    int chunk = b >> 3, s = b & 7;
    int lo = s * NSLICE, hi = lo + NSLICE;
    int4 d4, sr4; float4 w4;
    bool fill = (tid < 250);
    if (fill) {
        int e0 = chunk * CHUNK + tid * 4;
        d4  = *(const int4*)(dst + e0);
        sr4 = *(const int4*)(src + e0);
        w4  = *(const float4*)(ew + e0);
    }

    if (b < 2560) {
        // (a) X/H pack, one element per thread
        int t = b * 256 + tid;
        if (t < NE) {
            float4 x = X4[t];
            float4 h = H4[t];
            int n = t >> 5, q = t & 31;
            unsigned int* row = XH32 + n * 128;
            row[2 * q]          = pack2bf(x.x, x.y);
            row[2 * q + 1]      = pack2bf(x.z, x.w);
            row[64 + 2 * q]     = pack2bf(h.x, h.y);
            row[64 + 2 * q + 1] = pack2bf(h.z, h.w);
        }
    } else if (b < 2816) {
        // (a') weight transpose, coalesced reads: t covers 2048 rows x 32 float4
        int t = (b - 2560) * 256 + tid;      // < 65536
        int row = t >> 5;                    // row = g*512 + k
        int g = row >> 9, k = row & 511;
        int o = (t & 31) * 4;
        const float* Wb; int kk;
        if (k < 128)      { Wb = Wx_l; kk = k; }
        else if (k < 256) { Wb = Wx_r; kk = k - 128; }
        else if (k < 384) { Wb = Wh_l; kk = k - 256; }
        else              { Wb = Wh_r; kk = k - 384; }
        float4 w = *(const float4*)(Wb + g * 16384 + kk * 128 + o);
        int ci = k >> 5, jg = (k >> 3) & 3, off = k & 7;
        unsigned short* wp = Wsz + ci * 16384 + jg * 4096 + (g * 128 + o) * 8 + off;
        wp[0]  = f2bf(w.x);
        wp[8]  = f2bf(w.y);
        wp[16] = f2bf(w.z);
        wp[24] = f2bf(w.w);
        if (k == 0) {
            int j0 = g * 128 + o;
#pragma unroll
            for (int i = 0; i < 4; ++i)
                bias[j0 + i] = bx[j0 + i] + bh[j0 + i] + bg[j0 + i];
        }
    }

    // (b) slice-filtered bump fill: 4 independent chains per thread
    if (fill) {
        int dv[4] = {d4.x, d4.y, d4.z, d4.w};
        int sv[4] = {sr4.x, sr4.y, sr4.z, sr4.w};
        float wv[4] = {w4.x, w4.y, w4.z, w4.w};
#pragma unroll
        for (int k = 0; k < 4; ++k) {
            int d = dv[k];
            if (d >= lo && d < hi) {
                int p = atomicAdd(&cnt[d], 1);
                if (p < SEG)
                    s_p[d * SEG + p] = (unsigned int)sv[k] | ((unsigned int)f2bf(wv[k]) << 16);
            }
        }
    }
}

// One wave per node (lane owns 8 B of the 512 B row). 16-edge manual unroll:
// 16 independent row gathers in flight per lane. Block->node mapping matches
// fill's XCD slicing so segment reads hit the local L2.
__global__ void __launch_bounds__(256)
aggregate_kernel(const uint2* __restrict__ XH64,
                 const int* __restrict__ cnt,
                 const unsigned int* __restrict__ s_p,
                 uint2* __restrict__ AGG64) {
    int wv = threadIdx.x >> 6, lane = threadIdx.x & 63;
    int b = blockIdx.x;                 // 0..4999
    int s = b & 7, j = b >> 3;          // j: 0..624
    int n = s * NSLICE + j * 4 + wv;
    int deg = cnt[n];
    int m = (deg < SEG) ? deg : SEG;
    const unsigned int* seg = s_p + (size_t)n * SEG;
    float a0 = 0.f, a1 = 0.f, a2 = 0.f, a3 = 0.f;
    int i = 0;
    for (; i + 16 <= m; i += 16) {
        unsigned int e[16];
        uint2 u[16];
#pragma unroll
        for (int k = 0; k < 16; ++k) e[k] = seg[i + k];
#pragma unroll
        for (int k = 0; k < 16; ++k) u[k] = XH64[(size_t)(e[k] & 0xffff) * 64 + lane];
#pragma unroll
        for (int k = 0; k < 16; ++k) {
            float w = __int_as_float(e[k] & 0xffff0000u);
            a0 += bf_lo(u[k].x) * w;
            a1 += bf_hi(u[k].x) * w;
            a2 += bf_lo(u[k].y) * w;
            a3 += bf_hi(u[k].y) * w;
        }
    }
    for (; i + 4 <= m; i += 4) {
        unsigned int e[4];
        uint2 u[4];
#pragma unroll
        for (int k = 0; k < 4; ++k) e[k] = seg[i + k];
#pragma unroll
        for (int k = 0; k < 4; ++k) u[k] = XH64[(size_t)(e[k] & 0xffff) * 64 + lane];
#pragma unroll
        for (int k = 0; k < 4; ++k) {
            float w = __int_as_float(e[k] & 0xffff0000u);
            a0 += bf_lo(u[k].x) * w;
            a1 += bf_hi(u[k].x) * w;
            a2 += bf_lo(u[k].y) * w;
            a3 += bf_hi(u[k].y) * w;
        }
    }
    for (; i < m; ++i) {
        unsigned int e = seg[i];
        float w = __int_as_float(e & 0xffff0000u);
        uint2 u = XH64[(size_t)(e & 0xffff) * 64 + lane];
        a0 += bf_lo(u.x) * w;
        a1 += bf_hi(u.x) * w;
        a2 += bf_lo(u.y) * w;
        a3 += bf_hi(u.y) * w;
    }
    float inv = (deg > 0) ? 1.0f / (float)deg : 1.0f;
    uint2 r;
    r.x = pack2bf(a0 * inv, a1 * inv);
    r.y = pack2bf(a2 * inv, a3 * inv);
    AGG64[(size_t)n * 64 + lane] = r;
}

// Fused GEMM + peephole-LSTM, N-split for occupancy.
// 1250 blocks = 625 M-tiles x 2 column-halves. Block (t,h) computes rows
// [t*32, t*32+32) x output cols cg0 in [h*64, h*64+64) for ALL 4 gates
// (256 of the 512 GEMM cols) -> the in-register LSTM epilogue still holds.
// LDS: double-buffered 2 x 16 KB -> 32 KB/block, 4 blocks/CU (16 waves/CU).
__global__ void __launch_bounds__(256)
gemm_lstm_kernel(const unsigned short* __restrict__ XH,
                 const unsigned short* __restrict__ AGG,
                 const unsigned short* __restrict__ Wsz,
                 const float* __restrict__ bias,
                 const float* __restrict__ wc,
                 const float* __restrict__ C,
                 float* __restrict__ out) {
    __shared__ __align__(16) short Bs[2][8192];  // [buf][jg*2048 + g*512 + c64*8 + off]

    int tid = threadIdx.x;
    int wv = tid >> 6, lane = tid & 63;
    int lm = lane & 15, lq = lane >> 4;
    int bid = blockIdx.x;
    int m0 = (bid >> 1) * 32;
    int hb = (bid & 1) * 512;           // half-offset in shorts: h*64 cols * 8

    floatx4 acc[2][4];
#pragma unroll
    for (int mt = 0; mt < 2; ++mt)
#pragma unroll
        for (int g = 0; g < 4; ++g) acc[mt][g] = (floatx4)(0.f);

    // stage chunk 0 into buf 0: wave wv stages (jg=wv, g=0..3), 1 KB each
#pragma unroll
    for (int g = 0; g < 4; ++g)
        load_lds16(Wsz + wv * 4096 + g * 1024 + hb + lane * 8,
                   &Bs[0][wv * 2048 + g * 512]);

    // A prefetch for kb=0 (segment aggX, offset 0 in AGG)
    short8 ca0, ca1;
    {
        const unsigned short* ar = AGG + (size_t)(m0 + lm) * 256 + lq * 8;
        ca0 = *(const short8*)ar;
        ca1 = *(const short8*)(ar + 16 * 256);
    }

    for (int it = 0; it < 16; ++it) {
        __syncthreads();   // drains staging (vmcnt0) + guards buffer reuse
        if (it < 15) {
            const unsigned short* wb = Wsz + (it + 1) * 16384 + wv * 4096 + hb;
            short* lb = &Bs[(it + 1) & 1][wv * 2048];
#pragma unroll
            for (int g = 0; g < 4; ++g)
                load_lds16(wb + g * 1024 + lane * 8, &lb[g * 512]);
        }
        // A prefetch for next iter
        short8 na0, na1;
        if (it < 15) {
            int kn = (it + 1) * 32;
            const unsigned short* ab = (kn & 128) ? XH : AGG;
            int aoff = (kn & 127) | ((kn & 256) >> 1);
            const unsigned short* arn = ab + (size_t)(m0 + lm) * 256 + aoff + lq * 8;
            na0 = *(const short8*)arn;
            na1 = *(const short8*)(arn + 16 * 256);
        }
        // B frags from LDS (conflict-free) + MFMA
        const short* bsc = Bs[it & 1];
#pragma unroll
        for (int g = 0; g < 4; ++g) {
            short8 bfr = *(const short8*)&bsc[(lq << 11) + (g << 9) + ((wv << 4) + lm) * 8];
            acc[0][g] = __builtin_amdgcn_mfma_f32_16x16x32_bf16(ca0, bfr, acc[0][g], 0, 0, 0);
            acc[1][g] = __builtin_amdgcn_mfma_f32_16x16x32_bf16(ca1, bfr, acc[1][g], 0, 0, 0);
        }
        ca0 = na0; ca1 = na1;
    }

    // epilogue: bias/peephole loads here (keeps K-loop register pressure low)
    int cg0 = (hb >> 3) + (wv << 4) + lm;   // hb/8 = h*64
    float bG[4], wP[3];
#pragma unroll
    for (int g = 0; g < 4; ++g) bG[g] = bias[(g << 7) + cg0];
#pragma unroll
    for (int j = 0; j < 3; ++j) wP[j] = wc[j * 128 + cg0];

#pragma unroll
    for (int mt = 0; mt < 2; ++mt)
#pragma unroll
        for (int r = 0; r < 4; ++r) {
            int row = m0 + mt * 16 + lq * 4 + r;   // 625*32 == NN exact, no guard
            float c = C[(size_t)row * D + cg0];
            float pi = acc[mt][0][r] + bG[0] + wP[0] * c;
            float pf = acc[mt][1][r] + bG[1] + wP[1] * c;
            float pt = acc[mt][2][r] + bG[2];
            float po = acc[mt][3][r] + bG[3];
            float I = sigm(pi);
            float F = sigm(pf);
            float T = tanhx(pt);
            float cn = F * c + I * T;
            float O = sigm(po + wP[2] * cn);
            out[(size_t)row * D + cg0] = O * tanhx(cn);
            out[(size_t)NN * D + (size_t)row * D + cg0] = cn;
        }
}

extern "C" void kernel_launch(void* const* d_in, const int* in_sizes, int n_in,
                              void* d_out, int out_size, void* d_ws, size_t ws_size,
                              hipStream_t stream) {
    const float* X  = (const float*)d_in[0];
    const int* ei   = (const int*)d_in[1];
    const float* ew = (const float*)d_in[2];
    const float* H  = (const float*)d_in[3];
    const float* C  = (const float*)d_in[4];
    const float* Wx_l = (const float*)d_in[5];
    const float* Wx_r = (const float*)d_in[6];
    const float* bx   = (const float*)d_in[7];
    const float* Wh_l = (const float*)d_in[8];
    const float* Wh_r = (const float*)d_in[9];
    const float* bh   = (const float*)d_in[10];
    const float* wc   = (const float*)d_in[11];
    const float* bg   = (const float*)d_in[12];
    float* out = (float*)d_out;

    const int* src = ei;
    const int* dst = ei + NE;

    // workspace layout (16B aligned), ~31.3 MB
    char* ws = (char*)d_ws;
    int* cnt = (int*)(ws + 0);                                //     80,000 B
    unsigned int* s_p = (unsigned int*)(ws + 80128);          // 10,240,000 B (20000*128*4)
    unsigned short* XH  = (unsigned short*)(ws + 10320128);   // 10,240,000 B
    unsigned short* AGG = (unsigned short*)(ws + 20560128);   // 10,240,000 B
    unsigned short* Wsz = (unsigned short*)(ws + 30800128);   //    524,288 B
    float* bias = (float*)(ws + 31324416);                    //      2,048 B

    hipMemsetAsync(cnt, 0, NN * sizeof(int), stream);
    prep_fill_kernel<<<5120, 256, 0, stream>>>(src, dst, ew, cnt, s_p,
                                               (const float4*)X, (const float4*)H,
                                               (unsigned int*)XH,
                                               Wx_l, Wx_r, Wh_l, Wh_r,
                                               bx, bh, bg, Wsz, bias);
    aggregate_kernel<<<NN / 4, 256, 0, stream>>>((const uint2*)XH, cnt, s_p,
                                                 (uint2*)AGG);
    gemm_lstm_kernel<<<NTILES * 2, 256, 0, stream>>>(XH, AGG, Wsz, bias, wc, C, out);
}